// Round 3
// baseline (147.863 us; speedup 1.0000x reference)
//
#include <hip/hip_runtime.h>
#include <stdint.h>

#define NROWS 8192
#define KX    2048      // N*M
#define KA    2112      // KX + NF (augmented K)
#define NF    64
#define DD    2016
#define WCOLS 2080      // NF + DD
#define ODIM  1024
#define BN_EPS 1e-5f

#define A1_OT 32        // o-tile for build_a1
#define A2_DC 8         // d-chunks for build_a2
#define A2_DPC 252      // DD / A2_DC
#define A2_OT 16        // o-tile for build_a2

using f32x4  = __attribute__((ext_vector_type(4))) float;
using bf16x8 = __attribute__((ext_vector_type(8))) short;

__device__ __forceinline__ short f2bf(float x) {
    uint32_t u = __float_as_uint(x);
    uint32_t r = (u + 0x7FFFu + ((u >> 16) & 1u)) >> 16;   // RNE to bf16
    return (short)r;
}

__device__ __forceinline__ void gload16(const void* g, void* l) {
    __builtin_amdgcn_global_load_lds(
        (const __attribute__((address_space(1))) uint32_t*)g,
        (__attribute__((address_space(3))) uint32_t*)l, 16, 0, 0);
}

// ---------------------------------------------------------------------------
// Kernel 1: convert X (fp32) -> bf16 into augmented Xa[8192][2112];
// cols [0,2048) = bf16(x); cols [2048,2112) = bf16(sum_m x^2 - 32) per field.
// ---------------------------------------------------------------------------
__global__ __launch_bounds__(256) void convert_x(const float* __restrict__ X,
                                                 short* __restrict__ Xa) {
    const int row = blockIdx.x;
    const int t = threadIdx.x;
    const float4* xr = reinterpret_cast<const float4*>(X + (size_t)row * KX);
    float4 v0 = xr[t * 2];
    float4 v1 = xr[t * 2 + 1];
    bf16x8 s;
    s[0] = f2bf(v0.x); s[1] = f2bf(v0.y); s[2] = f2bf(v0.z); s[3] = f2bf(v0.w);
    s[4] = f2bf(v1.x); s[5] = f2bf(v1.y); s[6] = f2bf(v1.z); s[7] = f2bf(v1.w);
    short* outr = Xa + (size_t)row * KA;
    reinterpret_cast<bf16x8*>(outr)[t] = s;
    float sq = v0.x*v0.x + v0.y*v0.y + v0.z*v0.z + v0.w*v0.w
             + v1.x*v1.x + v1.y*v1.y + v1.z*v1.z + v1.w*v1.w;
    sq += __shfl_xor(sq, 1);
    sq += __shfl_xor(sq, 2);
    if ((t & 3) == 0) outr[KX + (t >> 2)] = f2bf(sq - 32.0f);  // centered
}

// ---------------------------------------------------------------------------
// Kernel 2: A1[o][k] = sum_{d<64} Wa[o][d] * Wz[d][k] -> bf16 Aw[o][0..2048)
// grid (KX/256=8, ODIM/A1_OT=32).  Thread caches its Wz column (64 f32) in
// VGPRs; Wa loads are block-uniform -> scalarized s_loads.  Wz L2 traffic
// 537 MB -> 17 MB vs round 2.
// ---------------------------------------------------------------------------
__global__ __launch_bounds__(256) void build_a1(const float* __restrict__ Wa,
                                                const float* __restrict__ Wz,
                                                short* __restrict__ Aw) {
    const int k = blockIdx.x * 256 + threadIdx.x;
    const int o0 = blockIdx.y * A1_OT;
    float wz[64];
#pragma unroll
    for (int d = 0; d < 64; ++d) wz[d] = Wz[(size_t)d * KX + k];
    for (int o = o0; o < o0 + A1_OT; ++o) {
        const float* war = Wa + (size_t)o * WCOLS;
        float acc = 0.f;
#pragma unroll
        for (int d = 0; d < 64; ++d) acc += war[d] * wz[d];
        Aw[(size_t)o * KA + k] = f2bf(acc);
    }
}

// ---------------------------------------------------------------------------
// Kernel 3a: A2 partials[chunk][o][n] = sum_{d in chunk} Wa2[o][d]*theta[d][n]^2
// grid (A2_DC=8, ODIM/A2_OT=64); block = 4 d-groups x 64 n-lanes.
// theta loaded once per d, reused for 16 o-FMAs (traffic 528 -> 33 MB).
// ---------------------------------------------------------------------------
__global__ __launch_bounds__(256) void build_a2(const float* __restrict__ Wa,
                                                const float* __restrict__ theta,
                                                float* __restrict__ partials) {
    const int n = threadIdx.x & 63;
    const int g = threadIdx.x >> 6;
    const int o0 = blockIdx.y * A2_OT;
    const int d0 = blockIdx.x * A2_DPC;
    float acc[A2_OT];
#pragma unroll
    for (int j = 0; j < A2_OT; ++j) acc[j] = 0.f;
    for (int i = g; i < A2_DPC; i += 4) {
        const int d = d0 + i;
        float th = theta[(size_t)d * NF + n];
        float th2 = th * th;
#pragma unroll
        for (int j = 0; j < A2_OT; ++j)
            acc[j] += Wa[(size_t)(o0 + j) * WCOLS + NF + d] * th2;
    }
    __shared__ float red[4][A2_OT][64];
#pragma unroll
    for (int j = 0; j < A2_OT; ++j) red[g][j][n] = acc[j];
    __syncthreads();
    const int t = threadIdx.x;
#pragma unroll
    for (int k = 0; k < A2_OT * 64 / 256; ++k) {
        const int idx = t + k * 256;
        const int ol = idx >> 6, nn = idx & 63;
        float s = red[0][ol][nn] + red[1][ol][nn] + red[2][ol][nn] + red[3][ol][nn];
        partials[((size_t)blockIdx.x * ODIM + o0 + ol) * NF + nn] = s;
    }
}

// Kernel 3b: reduce A2_DC partials -> bf16 Aw cols [2048,2112)
__global__ __launch_bounds__(256) void a2_reduce(const float* __restrict__ partials,
                                                 short* __restrict__ Aw) {
    const int idx = blockIdx.x * 256 + threadIdx.x;   // o*64+n
    const int o = idx >> 6, n = idx & 63;
    float s = 0.f;
#pragma unroll
    for (int c = 0; c < A2_DC; ++c)
        s += partials[((size_t)c * ODIM + o) * NF + n];
    Aw[(size_t)o * KA + KX + n] = f2bf(s);
}

// ---------------------------------------------------------------------------
// Kernel 4: main GEMM  C = Xa(8192x2112) * Aw(1024x2112)^T + bias, bf16 MFMA.
// Double-buffered LDS + prefetch-before-compute (minimum-2ph recipe):
//   iter t: STAGE(buf^1, t+1) issued first; ds_read+MFMA on buf; ONE barrier.
// Epilogue fuses bias add + BN column sum/sumsq partials (atomics).
// ---------------------------------------------------------------------------
__global__ __launch_bounds__(256) void gemm_kern(const short* __restrict__ Xa,
                                                 const short* __restrict__ Aw,
                                                 const float* __restrict__ bias,
                                                 float* __restrict__ C,
                                                 float* __restrict__ sums) {
    __shared__ __align__(16) short As[2][128 * 32];
    __shared__ __align__(16) short Bs[2][128 * 32];
    const int tid  = threadIdx.x;
    const int lane = tid & 63;
    const int wid  = tid >> 6;
    const int wr = wid >> 1, wc = wid & 1;
    const int bm = blockIdx.x * 128;
    const int bn = blockIdx.y * 128;

    f32x4 acc[4][4] = {};

    // Staging: chunk c (16B) at LDS pos c holds global slot q = (c&3) ^ ((r>>1)&3)
    const int c0 = tid, c1 = tid + 256;
    const int r0 = c0 >> 2, q0 = (c0 & 3) ^ ((r0 >> 1) & 3);
    const int r1 = c1 >> 2, q1 = (c1 & 3) ^ ((r1 >> 1) & 3);
    const short* gA0 = Xa + (size_t)(bm + r0) * KA + q0 * 8;
    const short* gA1 = Xa + (size_t)(bm + r1) * KA + q1 * 8;
    const short* gB0 = Aw + (size_t)(bn + r0) * KA + q0 * 8;
    const short* gB1 = Aw + (size_t)(bn + r1) * KA + q1 * 8;
    const int l0 = c0 * 8, l1 = c1 * 8;

    // Swizzled LDS read offsets
    const int lq = lane >> 4;
    int offA[4], offB[4];
#pragma unroll
    for (int m = 0; m < 4; ++m) {
        int ra = wr * 64 + m * 16 + (lane & 15);
        offA[m] = ra * 32 + (lq ^ ((ra >> 1) & 3)) * 8;
        int rb = wc * 64 + m * 16 + (lane & 15);
        offB[m] = rb * 32 + (lq ^ ((rb >> 1) & 3)) * 8;
    }

    const int NT = KA / 32;   // 66

    // prologue: stage tile 0 into buf 0
    gload16(gA0, &As[0][l0]);
    gload16(gA1, &As[0][l1]);
    gload16(gB0, &Bs[0][l0]);
    gload16(gB1, &Bs[0][l1]);
    __syncthreads();

    int cur = 0;
    for (int kt = 0; kt < NT; ++kt) {
        // 1) issue next-tile prefetch into the other buffer (hidden under compute)
        if (kt + 1 < NT) {
            const int ko = (kt + 1) * 32;
            gload16(gA0 + ko, &As[cur ^ 1][l0]);
            gload16(gA1 + ko, &As[cur ^ 1][l1]);
            gload16(gB0 + ko, &Bs[cur ^ 1][l0]);
            gload16(gB1 + ko, &Bs[cur ^ 1][l1]);
        }
        // 2) compute current buffer
        bf16x8 a[4], b[4];
#pragma unroll
        for (int m = 0; m < 4; ++m) a[m] = *reinterpret_cast<const bf16x8*>(&As[cur][offA[m]]);
#pragma unroll
        for (int n = 0; n < 4; ++n) b[n] = *reinterpret_cast<const bf16x8*>(&Bs[cur][offB[n]]);
#pragma unroll
        for (int m = 0; m < 4; ++m)
#pragma unroll
            for (int n = 0; n < 4; ++n)
                acc[m][n] = __builtin_amdgcn_mfma_f32_16x16x32_bf16(a[m], b[n], acc[m][n], 0, 0, 0);
        // 3) one barrier per K-step (implicit vmcnt(0) drains the prefetch)
        __syncthreads();
        cur ^= 1;
    }

    // Epilogue: C/D layout col=lane&15, row=(lane>>4)*4+reg (m89/m91 verified).
    // Fused: bias add, store, and BN column partial sum/sumsq.
    const int rlo = (lane >> 4) * 4;
    const int cl  = lane & 15;
#pragma unroll
    for (int n = 0; n < 4; ++n) {
        const int col = bn + wc * 64 + n * 16 + cl;
        const float bv = bias[col];
        float s = 0.f, q = 0.f;
#pragma unroll
        for (int m = 0; m < 4; ++m) {
            const int rowb = bm + wr * 64 + m * 16 + rlo;
#pragma unroll
            for (int r2 = 0; r2 < 4; ++r2) {
                float v = acc[m][n][r2] + bv;
                C[(size_t)(rowb + r2) * ODIM + col] = v;
                s += v; q += v * v;
            }
        }
        // reduce across the 4 row-groups (lanes sharing lane&15)
        s += __shfl_xor(s, 16); s += __shfl_xor(s, 32);
        q += __shfl_xor(q, 16); q += __shfl_xor(q, 32);
        if (lane < 16) {
            atomicAdd(&sums[col], s);
            atomicAdd(&sums[ODIM + col], q);
        }
    }
}

// Kernel 6: per-column scale/shift from sums
__global__ __launch_bounds__(256) void bn_finalize(float* __restrict__ sums,
                                                   const float* __restrict__ gamma,
                                                   const float* __restrict__ beta) {
    const int c = blockIdx.x * 256 + threadIdx.x;
    const float inv = 1.0f / (float)NROWS;
    float mean = sums[c] * inv;
    float var  = sums[ODIM + c] * inv - mean * mean;
    float sc   = gamma[c] * rsqrtf(var + BN_EPS);
    sums[2 * ODIM + c] = sc;
    sums[3 * ODIM + c] = beta[c] - mean * sc;
}

// Kernel 7: apply BN in place (float4)
__global__ __launch_bounds__(256) void bn_apply(float* __restrict__ C,
                                                const float* __restrict__ sums) {
    const float4* sc4 = reinterpret_cast<const float4*>(sums + 2 * ODIM);
    const float4* sh4 = reinterpret_cast<const float4*>(sums + 3 * ODIM);
    const size_t total = (size_t)NROWS * (ODIM / 4);
    for (size_t i = (size_t)blockIdx.x * 256 + threadIdx.x; i < total;
         i += (size_t)gridDim.x * 256) {
        const int c4 = (int)(i & (ODIM / 4 - 1));
        float4 v = reinterpret_cast<const float4*>(C)[i];
        float4 s = sc4[c4], h = sh4[c4];
        v.x = v.x * s.x + h.x;
        v.y = v.y * s.y + h.y;
        v.z = v.z * s.z + h.z;
        v.w = v.w * s.w + h.w;
        reinterpret_cast<float4*>(C)[i] = v;
    }
}

// ---------------------------------------------------------------------------
extern "C" void kernel_launch(void* const* d_in, const int* in_sizes, int n_in,
                              void* d_out, int out_size, void* d_ws, size_t ws_size,
                              hipStream_t stream) {
    const float* X     = (const float*)d_in[0];
    const float* Wz    = (const float*)d_in[1];
    const float* theta = (const float*)d_in[2];
    const float* Wa    = (const float*)d_in[3];
    const float* bias  = (const float*)d_in[4];
    const float* gamma = (const float*)d_in[5];
    const float* beta  = (const float*)d_in[6];
    float* out = (float*)d_out;

    char* ws = (char*)d_ws;
    float* sums = (float*)ws;                                        // 4*1024 f32
    short* Xa = (short*)(ws + 16384);                                // 8192*2112 bf16
    short* Aw = (short*)(ws + 16384 + (size_t)NROWS * KA * 2);       // 1024*2112 bf16
    float* partials = (float*)(ws + 16384 + (size_t)NROWS * KA * 2
                                        + (size_t)ODIM * KA * 2);    // 8*1024*64 f32

    hipMemsetAsync(sums, 0, 2 * ODIM * sizeof(float), stream);
    convert_x<<<NROWS, 256, 0, stream>>>(X, Xa);
    build_a1<<<dim3(KX / 256, ODIM / A1_OT), 256, 0, stream>>>(Wa, Wz, Aw);
    build_a2<<<dim3(A2_DC, ODIM / A2_OT), 256, 0, stream>>>(Wa, theta, partials);
    a2_reduce<<<ODIM * NF / 256, 256, 0, stream>>>(partials, Aw);
    gemm_kern<<<dim3(NROWS / 128, ODIM / 128), 256, 0, stream>>>(Xa, Aw, bias, out, sums);
    bn_finalize<<<ODIM / 256, 256, 0, stream>>>(sums, gamma, beta);
    bn_apply<<<2048, 256, 0, stream>>>(out, sums);
}